// Round 6
// baseline (897.786 us; speedup 1.0000x reference)
//
#include <hip/hip_runtime.h>
#include <hip/hip_bf16.h>

typedef __bf16 bf16;
typedef __attribute__((ext_vector_type(8))) __bf16 bf16x8;
typedef __attribute__((ext_vector_type(4))) float f32x4;

constexpr int N_NODES   = 100000;
constexpr int N_PAD     = 100032;   // multiple of 64
constexpr int D         = 128;
constexpr int D_FF      = 256;
constexpr int N_CLASSES = 26;
constexpr int N_GRAPHS  = 512;
constexpr int NB1       = 256;                       // partition blocks (CSR build)
constexpr int NBUCK     = (N_NODES + 511) / 512;     // 196 dst-buckets of 512 nodes

// R19: phase-partitioned persistent aggregation.
constexpr int KPH  = 13;     // phases: src>>13 (8192-node window = 2MiB bf16 rows)
constexpr int PST  = 14;     // P row stride (13 starts + end)
constexpr int NPB  = 196;    // nodes per persistent block
constexpr int PBLK = 512;    // persistent grid: 2 blocks/CU, all resident

__device__ inline float2 bf2f(unsigned u) {
    float lo = __uint_as_float(u << 16);
    float hi = __uint_as_float(u & 0xffff0000u);
    return make_float2(lo, hi);
}

__device__ inline void acc_row(float acc[8], uint4 u) {
    float2 f0 = bf2f(u.x), f1 = bf2f(u.y), f2 = bf2f(u.z), f3 = bf2f(u.w);
    acc[0] += f0.x; acc[1] += f0.y; acc[2] += f1.x; acc[3] += f1.y;
    acc[4] += f2.x; acc[5] += f2.y; acc[6] += f3.x; acc[7] += f3.y;
}

// ---------------- CSR build: atomic-free bucket counting sort ----------------

__global__ __launch_bounds__(1024) void p1_hist(const int* __restrict__ edst,
                                                int* __restrict__ gcount, int e) {
    __shared__ int cnt[NBUCK];
    for (int t = threadIdx.x; t < NBUCK; t += 1024) cnt[t] = 0;
    __syncthreads();
    int chunk = (e + NB1 - 1) / NB1;
    int lo = blockIdx.x * chunk;
    int hi = min(e, lo + chunk);
    for (int i = lo + threadIdx.x; i < hi; i += 1024)
        atomicAdd(&cnt[edst[i] >> 9], 1);
    __syncthreads();
    for (int t = threadIdx.x; t < NBUCK; t += 1024)
        gcount[t * NB1 + blockIdx.x] = cnt[t];
}

// scan1 writes EXCLUSIVE-within-chunk prefix; consumers add boff[chunk].
__global__ __launch_bounds__(256) void scan1(const int* __restrict__ in,
                                             int* out, int* bsum, int n) {
    __shared__ int sd[256];
    int i = blockIdx.x * 256 + threadIdx.x;
    int v = (i < n) ? in[i] : 0;
    sd[threadIdx.x] = v; __syncthreads();
    for (int off = 1; off < 256; off <<= 1) {
        int t = (threadIdx.x >= off) ? sd[threadIdx.x - off] : 0;
        __syncthreads();
        sd[threadIdx.x] += t;
        __syncthreads();
    }
    if (i < n) out[i] = sd[threadIdx.x] - v;     // exclusive within chunk
    if (threadIdx.x == 255) bsum[blockIdx.x] = sd[255];
}

__global__ __launch_bounds__(1024) void scan2k(const int* __restrict__ bsum,
                                               int* __restrict__ boff, int nb) {
    __shared__ int sd[1024];
    int t = threadIdx.x;
    int v = (t < nb) ? bsum[t] : 0;
    sd[t] = v; __syncthreads();
    for (int off = 1; off < 1024; off <<= 1) {
        int x = (t >= off) ? sd[t - off] : 0;
        __syncthreads();
        sd[t] += x;
        __syncthreads();
    }
    if (t < nb) boff[t] = sd[t] - v;  // exclusive
}

// misc: block 0 = starts (lower_bound); blocks 1..48 = castWT3; 49..64 = zero gsum.
__global__ __launch_bounds__(1024) void misc_kernel(const int* __restrict__ batch,
                                                    int* __restrict__ starts, int n,
                                                    const float* __restrict__ W0,
                                                    const float* __restrict__ W1,
                                                    const float* __restrict__ W2,
                                                    bf16* __restrict__ WT3,
                                                    float* __restrict__ gsum) {
    int t = threadIdx.x;
    if (blockIdx.x == 0) {
        if (t <= N_GRAPHS) {
            int lo = 0, hi = n;
            while (lo < hi) {
                int mid = (lo + hi) >> 1;
                if (batch[mid] < t) lo = mid + 1; else hi = mid;
            }
            starts[t] = lo;
        }
    } else if (blockIdx.x <= 48) {
        int idx = (blockIdx.x - 1) * 1024 + t;     // 0 .. 49151 == 3*128*128
        int l = idx >> 14;
        int rem = idx & 16383;
        int nn = rem >> 7;
        int kk = rem & 127;
        const float* W = (l == 0) ? W0 : (l == 1) ? W1 : W2;
        WT3[idx] = (bf16)W[kk * D + nn];           // WT3[l][n][k] = W[k][n]
    } else {
        int idx = (blockIdx.x - 49) * 1024 + t;    // 16384 float4 total
        f32x4 z = {0.f, 0.f, 0.f, 0.f};
        *((f32x4*)gsum + idx) = z;
    }
}

// scatter edges into dst-bucket-contiguous ebuf; pack (src<<9)|(dst&511)
__global__ __launch_bounds__(1024) void p3_scatter(const int* __restrict__ esrc,
                                                   const int* __restrict__ edst,
                                                   const int* __restrict__ gbase,
                                                   const int* __restrict__ boff,
                                                   int* __restrict__ ebuf, int e) {
    __shared__ int cur[NBUCK];
    for (int t = threadIdx.x; t < NBUCK; t += 1024)
        cur[t] = gbase[t * NB1 + blockIdx.x] + boff[t];
    __syncthreads();
    int chunk = (e + NB1 - 1) / NB1;
    int lo = blockIdx.x * chunk;
    int hi = min(e, lo + chunk);
    for (int i = lo + threadIdx.x; i < hi; i += 1024) {
        int d = edst[i], s = esrc[i];
        int pos = atomicAdd(&cur[d >> 9], 1);   // LDS atomic
        ebuf[pos] = (s << 9) | (d & 511);
    }
}

// R19 p45: per-(node,phase) counting sort. Outputs P[node][k] phase-segment
// offsets (k=0..13, P[13]=end), dinv, and csrc with each node's list grouped
// by src phase (src>>13). Phase of packed edge pe = pe>>22.
__global__ __launch_bounds__(1024) void p45_fill(const int* __restrict__ ebuf,
                                                 const int* __restrict__ gbase,
                                                 const int* __restrict__ boff,
                                                 float* __restrict__ dinv,
                                                 int* __restrict__ P,
                                                 int* __restrict__ csrc, int e, int n) {
    __shared__ int c2[512 * KPH];     // counts -> phase starts -> cursors
    __shared__ int ps[512];
    int b = blockIdx.x, t = threadIdx.x;
    for (int q = t; q < 512 * KPH; q += 1024) c2[q] = 0;
    __syncthreads();
    int lo = gbase[b * NB1] + boff[b];
    int hi = (b + 1 < NBUCK) ? gbase[(b + 1) * NB1] + boff[b + 1] : e;
    for (int i = lo + t; i < hi; i += 1024) {
        int pe = ebuf[i];
        atomicAdd(&c2[(pe & 511) * KPH + (pe >> 22)], 1);
    }
    __syncthreads();
    int tot = 0;
    if (t < 512) {
        for (int k = 0; k < KPH; ++k) {          // in-place excl. prefix per node
            int cc = c2[t * KPH + k];
            c2[t * KPH + k] = tot;
            tot += cc;
        }
        ps[t] = tot;
    }
    __syncthreads();
    for (int off = 1; off < 512; off <<= 1) {    // block scan over node totals
        int v = (t >= off && t < 512) ? ps[t - off] : 0;
        __syncthreads();
        if (t < 512) ps[t] += v;
        __syncthreads();
    }
    if (t < 512) {
        int g0 = lo + ps[t] - tot;               // global CSR slot of node
        int node = b * 512 + t;
        if (node < n) {
            dinv[node] = 1.0f / sqrtf((float)(tot + 1));   // +1 self-loop
            for (int k = 0; k < KPH; ++k) {
                int a = g0 + c2[t * KPH + k];
                P[node * PST + k] = a;
                c2[t * KPH + k] = a;             // absolute cursor
            }
            P[node * PST + KPH] = g0 + tot;
        }
    }
    __syncthreads();
    for (int i = lo + t; i < hi; i += 1024) {
        int pe = ebuf[i];
        int pos = atomicAdd(&c2[(pe & 511) * KPH + (pe >> 22)], 1);
        csrc[pos] = pe >> 9;
    }
}

// ---------------- dense compute ----------------

// Layer-1: C[row][:] = bf16( dinv[row] * ((f32)A @ W)[row][:] ) — gather table g1.
__global__ __launch_bounds__(256) void gemm_f32_kernel(const float* __restrict__ A,
                                                       const bf16* __restrict__ WT,
                                                       bf16* __restrict__ C,
                                                       const float* __restrict__ dinv, int n) {
    int wave = threadIdx.x >> 6;
    int lane = threadIdx.x & 63;
    int m16  = lane & 15;
    int quad = lane >> 4;
    int row0 = blockIdx.x * 64 + wave * 16;
    int arowi = row0 + m16;

    bf16x8 a[4];
    const float* arow = A + (size_t)arowi * D + quad * 8;
#pragma unroll
    for (int kt = 0; kt < 4; ++kt) {
        float4 f0 = make_float4(0.f, 0.f, 0.f, 0.f);
        float4 f1 = make_float4(0.f, 0.f, 0.f, 0.f);
        if (arowi < n) {
            f0 = *(const float4*)(arow + kt * 32);
            f1 = *(const float4*)(arow + kt * 32 + 4);
        }
        bf16x8 v = { (bf16)f0.x, (bf16)f0.y, (bf16)f0.z, (bf16)f0.w,
                     (bf16)f1.x, (bf16)f1.y, (bf16)f1.z, (bf16)f1.w };
        a[kt] = v;
    }

    float sc[4];
#pragma unroll
    for (int r = 0; r < 4; ++r) {
        int rr = row0 + quad * 4 + r;
        sc[r] = (rr < n) ? dinv[rr] : 0.f;
    }

#pragma unroll
    for (int nt = 0; nt < 8; ++nt) {
        f32x4 acc = {0.f, 0.f, 0.f, 0.f};
        const bf16* brow = WT + (nt * 16 + m16) * D + quad * 8;
#pragma unroll
        for (int kt = 0; kt < 4; ++kt) {
            bf16x8 b = *(const bf16x8*)(brow + kt * 32);
            acc = __builtin_amdgcn_mfma_f32_16x16x32_bf16(a[kt], b, acc, 0, 0, 0);
        }
#pragma unroll
        for (int r = 0; r < 4; ++r)
            C[(row0 + quad * 4 + r) * D + nt * 16 + m16] = (bf16)(sc[r] * acc[r]);
    }
}

// ---------------- R19 persistent phase-major aggregation core ----------------
// Block (512 thr = 32 groups of 16 lanes) owns NPB consecutive nodes; slot i
// covers nodes base+i*32..+31. acc[i] held in registers across all phases.
// Phase k gathers only srcs in [k*8192,(k+1)*8192) — 2MiB window, L2-resident
// chip-wide because all 512 blocks are co-resident and phase-aligned.
__device__ inline void pagg(const bf16* __restrict__ h,
                            const int* __restrict__ P,
                            const int* __restrict__ csrc,
                            int base, int g, int c, int n, float acc[7][8]) {
#pragma unroll
    for (int i = 0; i < 7; ++i) {
#pragma unroll
        for (int d = 0; d < 8; ++d) acc[i][d] = 0.f;
        int v = base + i * 32 + g;
        if (i * 32 + g < NPB && v < n) {          // self-loop term (streaming read)
            uint4 u = *(const uint4*)(h + (size_t)v * D + c * 8);
            acc_row(acc[i], u);
        }
    }
    for (int k = 0; k < KPH; ++k) {
#pragma unroll
        for (int i = 0; i < 7; ++i) {
            int v = base + i * 32 + g;
            if (i * 32 + g >= NPB || v >= n) continue;
            int s = P[v * PST + k], e = P[v * PST + k + 1];
            int j = s;
            for (; j + 1 < e; j += 2) {
                int s0 = csrc[j], s1 = csrc[j + 1];
                uint4 u0 = *(const uint4*)(h + (size_t)s0 * D + c * 8);
                uint4 u1 = *(const uint4*)(h + (size_t)s1 * D + c * 8);
                acc_row(acc[i], u0);
                acc_row(acc[i], u1);
            }
            if (j < e) {
                int s0 = csrc[j];
                uint4 u0 = *(const uint4*)(h + (size_t)s0 * D + c * 8);
                acc_row(acc[i], u0);
            }
        }
    }
}

// Persistent fused agg + W_{l+1} GEMM: g' = dinv * (relu(dv*acc + b) @ WT)
__global__ __launch_bounds__(512, 4) void pspmm_gemm_kernel(const bf16* __restrict__ h,
                                                            const int* __restrict__ P,
                                                            const int* __restrict__ csrc,
                                                            const float* __restrict__ dinv,
                                                            const float* __restrict__ bias,
                                                            const bf16* __restrict__ WT,
                                                            bf16* __restrict__ C, int n) {
    __shared__ bf16 tile[32][136];               // +8 bf16 row pad
    int t = threadIdx.x;
    int g = t >> 4, c = t & 15;
    int base = blockIdx.x * NPB;
    float acc[7][8];
    pagg(h, P, csrc, base, g, c, n, acc);

    int wave = t >> 6, lane = t & 63;
    int m16 = lane & 15, quad = lane >> 4;
    int tr0 = (wave >= 4) ? 16 : 0;              // waves 0-3: rows 0-15; 4-7: 16-31
    int ntq = (wave & 3) * 2;
    float4 bi0 = *(const float4*)(bias + c * 8);
    float4 bi1 = *(const float4*)(bias + c * 8 + 4);

#pragma unroll
    for (int i = 0; i < 7; ++i) {
        int v = base + i * 32 + g;
        bool val = (i * 32 + g < NPB) && (v < n);
        float dv = val ? dinv[v] : 0.f;
        bf16x8 o;
        o[0] = val ? (bf16)fmaxf(fmaf(dv, acc[i][0], bi0.x), 0.f) : (bf16)0.f;
        o[1] = val ? (bf16)fmaxf(fmaf(dv, acc[i][1], bi0.y), 0.f) : (bf16)0.f;
        o[2] = val ? (bf16)fmaxf(fmaf(dv, acc[i][2], bi0.z), 0.f) : (bf16)0.f;
        o[3] = val ? (bf16)fmaxf(fmaf(dv, acc[i][3], bi0.w), 0.f) : (bf16)0.f;
        o[4] = val ? (bf16)fmaxf(fmaf(dv, acc[i][4], bi1.x), 0.f) : (bf16)0.f;
        o[5] = val ? (bf16)fmaxf(fmaf(dv, acc[i][5], bi1.y), 0.f) : (bf16)0.f;
        o[6] = val ? (bf16)fmaxf(fmaf(dv, acc[i][6], bi1.z), 0.f) : (bf16)0.f;
        o[7] = val ? (bf16)fmaxf(fmaf(dv, acc[i][7], bi1.w), 0.f) : (bf16)0.f;
        __syncthreads();                          // tile reuse from prev i
        *(bf16x8*)(&tile[g][c * 8]) = o;
        __syncthreads();

        bf16x8 a[4];
#pragma unroll
        for (int kt = 0; kt < 4; ++kt)
            a[kt] = *(const bf16x8*)(&tile[tr0 + m16][quad * 8 + kt * 32]);
        float sc[4];
#pragma unroll
        for (int r = 0; r < 4; ++r) {
            int lr = i * 32 + tr0 + quad * 4 + r;
            int rr = base + lr;
            sc[r] = (lr < NPB && rr < n) ? dinv[rr] : 0.f;
        }
#pragma unroll
        for (int nt2 = 0; nt2 < 2; ++nt2) {
            int nt = ntq + nt2;
            f32x4 q = {0.f, 0.f, 0.f, 0.f};
            const bf16* brow = WT + (nt * 16 + m16) * D + quad * 8;
#pragma unroll
            for (int kt = 0; kt < 4; ++kt) {
                bf16x8 bfr = *(const bf16x8*)(brow + kt * 32);
                q = __builtin_amdgcn_mfma_f32_16x16x32_bf16(a[kt], bfr, q, 0, 0, 0);
            }
#pragma unroll
            for (int r = 0; r < 4; ++r) {
                int lr = i * 32 + tr0 + quad * 4 + r;
                int rr = base + lr;
                if (lr < NPB && rr < n)
                    C[(size_t)rr * D + nt * 16 + m16] = (bf16)(sc[r] * q[r]);
            }
        }
    }
}

// Persistent last-layer agg fused with mean-pool accumulation.
__global__ __launch_bounds__(512, 4) void pspmm_pool_kernel(const bf16* __restrict__ h,
                                                            const int* __restrict__ P,
                                                            const int* __restrict__ csrc,
                                                            const float* __restrict__ dinv,
                                                            const float* __restrict__ bias,
                                                            const int* __restrict__ batch,
                                                            float* __restrict__ gsum, int n) {
    __shared__ float tile[32][D];
    __shared__ int gid[32];
    int t = threadIdx.x;
    int g = t >> 4, c = t & 15;
    int base = blockIdx.x * NPB;
    float acc[7][8];
    pagg(h, P, csrc, base, g, c, n, acc);

    float4 bi0 = *(const float4*)(bias + c * 8);
    float4 bi1 = *(const float4*)(bias + c * 8 + 4);
#pragma unroll
    for (int i = 0; i < 7; ++i) {
        int v = base + i * 32 + g;
        bool val = (i * 32 + g < NPB) && (v < n);
        float dv = val ? dinv[v] : 0.f;
        float r0 = val ? fmaxf(fmaf(dv, acc[i][0], bi0.x), 0.f) : 0.f;
        float r1 = val ? fmaxf(fmaf(dv, acc[i][1], bi0.y), 0.f) : 0.f;
        float r2 = val ? fmaxf(fmaf(dv, acc[i][2], bi0.z), 0.f) : 0.f;
        float r3 = val ? fmaxf(fmaf(dv, acc[i][3], bi0.w), 0.f) : 0.f;
        float r4 = val ? fmaxf(fmaf(dv, acc[i][4], bi1.x), 0.f) : 0.f;
        float r5 = val ? fmaxf(fmaf(dv, acc[i][5], bi1.y), 0.f) : 0.f;
        float r6 = val ? fmaxf(fmaf(dv, acc[i][6], bi1.z), 0.f) : 0.f;
        float r7 = val ? fmaxf(fmaf(dv, acc[i][7], bi1.w), 0.f) : 0.f;
        __syncthreads();
        tile[g][c * 8 + 0] = r0; tile[g][c * 8 + 1] = r1;
        tile[g][c * 8 + 2] = r2; tile[g][c * 8 + 3] = r3;
        tile[g][c * 8 + 4] = r4; tile[g][c * 8 + 5] = r5;
        tile[g][c * 8 + 6] = r6; tile[g][c * 8 + 7] = r7;
        if (c == 0) gid[g] = val ? batch[v] : -1;
        __syncthreads();
        if (t < D) {
            int curg = gid[0];
            float sum = 0.f;
            if (curg >= 0) {
#pragma unroll 1
                for (int kk = 0; kk < 32; ++kk) {
                    int gg = gid[kk];
                    if (gg < 0) break;           // padding only trails
                    if (gg != curg) {
                        atomicAdd(&gsum[(size_t)curg * D + t], sum);
                        curg = gg; sum = 0.f;
                    }
                    sum += tile[kk][t];
                }
                atomicAdd(&gsum[(size_t)curg * D + t], sum);
            }
        }
    }
}

// FC head over pooled sums: pr = gsum/count, 2-layer MLP. One block/graph.
__global__ __launch_bounds__(256) void fc_head_kernel(const float* __restrict__ gsum,
                                                      const int* __restrict__ starts,
                                                      const float* __restrict__ Wfc,
                                                      const float* __restrict__ bfc,
                                                      const float* __restrict__ Wfc2,
                                                      const float* __restrict__ bfc2,
                                                      float* __restrict__ out) {
    __shared__ float pr[D];
    __shared__ float hid[D_FF];
    __shared__ float red[N_CLASSES][9];
    int g = blockIdx.x, t = threadIdx.x;
    if (t < D) {
        float ccount = fmaxf((float)(starts[g + 1] - starts[g]), 1.0f);
        pr[t] = gsum[(size_t)g * D + t] / ccount;
    }
    __syncthreads();
    float a0 = 0.f, a1 = 0.f, a2 = 0.f, a3 = 0.f;
    for (int k = 0; k < D; k += 4) {
        a0 = fmaf(pr[k],     Wfc[k * D_FF + t],       a0);
        a1 = fmaf(pr[k + 1], Wfc[(k + 1) * D_FF + t], a1);
        a2 = fmaf(pr[k + 2], Wfc[(k + 2) * D_FF + t], a2);
        a3 = fmaf(pr[k + 3], Wfc[(k + 3) * D_FF + t], a3);
    }
    hid[t] = fmaxf((a0 + a1) + (a2 + a3) + bfc[t], 0.f);
    __syncthreads();
    if (t < N_CLASSES * 8) {
        int cls = t >> 3, kk = t & 7;
        float o = 0.f;
        for (int k = kk; k < D_FF; k += 8)
            o = fmaf(hid[k], Wfc2[k * N_CLASSES + cls], o);
        red[cls][kk] = o;
    }
    __syncthreads();
    if (t < N_CLASSES) {
        float o = bfc2[t];
#pragma unroll
        for (int k = 0; k < 8; ++k) o += red[t][k];
        out[g * N_CLASSES + t] = o;
    }
}

// ---------------- launch ----------------

extern "C" void kernel_launch(void* const* d_in, const int* in_sizes, int n_in,
                              void* d_out, int out_size, void* d_ws, size_t ws_size,
                              hipStream_t stream) {
    const float* x     = (const float*)d_in[0];
    const int*   eidx  = (const int*)d_in[1];
    const int*   batch = (const int*)d_in[2];
    const float* W[3]  = { (const float*)d_in[3], (const float*)d_in[5], (const float*)d_in[7] };
    const float* b[3]  = { (const float*)d_in[4], (const float*)d_in[6], (const float*)d_in[8] };
    const float* Wfc   = (const float*)d_in[9];
    const float* bfc   = (const float*)d_in[10];
    const float* Wfc2  = (const float*)d_in[11];
    const float* bfc2  = (const float*)d_in[12];
    float* out = (float*)d_out;

    const int E = in_sizes[1] / 2;           // 3,200,000
    const int N = in_sizes[0] / D;           // 100,000
    const int* esrc = eidx;
    const int* edst = eidx + E;

    uint8_t* base = (uint8_t*)d_ws;
    size_t off = 0;
    auto alloc = [&](size_t bytes) -> void* {
        void* p = base + off;
        off = (off + bytes + 255) & ~(size_t)255;
        return p;
    };
    bf16*  hA     = (bf16*) alloc((size_t)N_PAD * D * 2);   // bf16 gather table
    bf16*  hB     = (bf16*) alloc((size_t)N_PAD * D * 2);
    bf16*  WT3    = (bf16*) alloc((size_t)3 * D * D * 2);
    int*   csrc   = (int*)  alloc((size_t)E * 4);
    int*   ebuf   = (int*)  alloc((size_t)E * 4);
    int*   gcount = (int*)  alloc((size_t)NBUCK * NB1 * 4);
    int*   gbase  = (int*)  alloc((size_t)(NBUCK * NB1 + 1) * 4);
    int*   P      = (int*)  alloc((size_t)N_PAD * PST * 4); // phase offsets
    float* dinv   = (float*)alloc((size_t)N * 4);
    int*   bsum   = (int*)  alloc(4096);
    int*   boff   = (int*)  alloc(4096);
    int*   starts = (int*)  alloc((size_t)(N_GRAPHS + 1) * 4);
    float* gsum   = (float*)alloc((size_t)N_GRAPHS * D * 4);
    (void)ws_size; (void)n_in; (void)out_size;

    const int GB  = N_PAD / 64;                         // 1563
    const int GCN = NBUCK * NB1;                        // 50176
    const int GCB = (GCN + 255) / 256;                  // 196

    // CSR build (single dst pass; phase partition happens inside p45)
    p1_hist<<<NB1, 1024, 0, stream>>>(edst, gcount, E);
    scan1<<<GCB, 256, 0, stream>>>(gcount, gbase, bsum, GCN);
    scan2k<<<1, 1024, 0, stream>>>(bsum, boff, GCB);
    misc_kernel<<<65, 1024, 0, stream>>>(batch, starts, N, W[0], W[1], W[2], WT3, gsum);
    p3_scatter<<<NB1, 1024, 0, stream>>>(esrc, edst, gbase, boff, ebuf, E);
    p45_fill<<<NBUCK, 1024, 0, stream>>>(ebuf, gbase, boff, dinv, P, csrc, E, N);

    // layer 1 input-side GEMM: g1 = dinv * (x @ W1)
    gemm_f32_kernel<<<GB, 256, 0, stream>>>(x, WT3, hA, dinv, N);
    // persistent fused layer1-agg + W2
    pspmm_gemm_kernel<<<PBLK, 512, 0, stream>>>(hA, P, csrc, dinv, b[0],
                                                WT3 + (size_t)1 * D * D, hB, N);
    // persistent fused layer2-agg + W3
    pspmm_gemm_kernel<<<PBLK, 512, 0, stream>>>(hB, P, csrc, dinv, b[1],
                                                WT3 + (size_t)2 * D * D, hA, N);
    // persistent layer3-agg + mean-pool
    pspmm_pool_kernel<<<PBLK, 512, 0, stream>>>(hA, P, csrc, dinv, b[2],
                                                batch, gsum, N);

    // FC head on pooled sums
    fc_head_kernel<<<N_GRAPHS, 256, 0, stream>>>(gsum, starts, Wfc, bfc, Wfc2, bfc2, out);
}